// Round 1
// baseline (138.063 us; speedup 1.0000x reference)
//
#include <hip/hip_runtime.h>
#include <hip/hip_bf16.h>

// Lightning attention, B=2 H=16 N=4096 D=128, BLOCK=128, nb=32.
// 3 passes: (1) per-chunk KV^T via MFMA, (2) elementwise decay-scan over chunks,
// (3) per-chunk output (scores + intra-decay + P@V + qdecay*(q@S)).

#define LDB   136   // LDS row stride in elements (272B: 16B-aligned, breaks bank conflicts)
#define NB    32
#define HH    16
#define NSEQ  4096

typedef float  f32x4  __attribute__((ext_vector_type(4)));
typedef __bf16 bf16x8 __attribute__((ext_vector_type(8)));
typedef unsigned short u16x8 __attribute__((ext_vector_type(8)));
typedef unsigned short u16x4 __attribute__((ext_vector_type(4)));

// float -> bf16 bits, round-to-nearest-even
__device__ __forceinline__ unsigned short f2bf(float f) {
  unsigned int u = __float_as_uint(f);
  unsigned int r = (u + 0x7fffu + ((u >> 16) & 1u)) >> 16;
  return (unsigned short)r;
}

// Stage 128x128 fp32 (row-major) -> LDS bf16 [128][LDB], row-major.
__device__ __forceinline__ void stage_row(const float* __restrict__ src,
                                          unsigned short* dst, int tid) {
#pragma unroll
  for (int i = 0; i < 16; ++i) {
    int idx = i * 256 + tid;      // 0..4095 float4s
    int row = idx >> 5;           // 0..127
    int q4  = idx & 31;           // 0..31
    const float4 vv = *reinterpret_cast<const float4*>(src + row * 128 + q4 * 4);
    u16x4 w;
    w[0] = f2bf(vv.x); w[1] = f2bf(vv.y); w[2] = f2bf(vv.z); w[3] = f2bf(vv.w);
    *reinterpret_cast<u16x4*>(dst + row * LDB + q4 * 4) = w;
  }
}

// Stage 128x128 fp32 (row-major [tau][d]) -> LDS bf16 transposed [d][LDB]=src[tau][d].
// Coalesced global reads (lanes sweep d); 8B LDS row writes (~4-way conflict max).
__device__ __forceinline__ void stage_transpose(const float* __restrict__ src,
                                                unsigned short* dst, int tid) {
#pragma unroll
  for (int i = 0; i < 16; ++i) {
    int idx = i * 256 + tid;      // 0..4095
    int d   = idx & 127;
    int tq  = idx >> 7;           // 0..31 (tau group of 4)
    u16x4 w;
#pragma unroll
    for (int j = 0; j < 4; ++j)
      w[j] = f2bf(src[(tq * 4 + j) * 128 + d]);
    *reinterpret_cast<u16x4*>(dst + d * LDB + tq * 4) = w;
  }
}

// Same, but scale column tau by exp(-sl*(BLOCK - tau))  (k_decay).
__device__ __forceinline__ void stage_transpose_scaled(const float* __restrict__ src,
                                                       unsigned short* dst, int tid,
                                                       float sl) {
#pragma unroll
  for (int i = 0; i < 16; ++i) {
    int idx = i * 256 + tid;
    int d   = idx & 127;
    int tq  = idx >> 7;
    u16x4 w;
#pragma unroll
    for (int j = 0; j < 4; ++j) {
      int tau = tq * 4 + j;
      float kd = expf(-sl * (float)(128 - tau));
      w[j] = f2bf(src[tau * 128 + d] * kd);
    }
    *reinterpret_cast<u16x4*>(dst + d * LDB + tq * 4) = w;
  }
}

// One 128x128x128 matmul: D += A(128xK=128 row-major in LDS) * B, where BT holds B^T
// row-major in LDS (BT[n][k]). Wave computes 64x64 quadrant (wr,wc). acc[4][4] f32x4.
__device__ __forceinline__ void mm128(const unsigned short* A, const unsigned short* BT,
                                      int lane, int wr, int wc, f32x4 acc[4][4]) {
  const int lr = lane & 15;
  const int lg = lane >> 4;
#pragma unroll
  for (int kk = 0; kk < 4; ++kk) {
    const int kb = kk * 32 + lg * 8;
    bf16x8 af[4], bf_[4];
#pragma unroll
    for (int m = 0; m < 4; ++m) {
      u16x8 raw = *reinterpret_cast<const u16x8*>(A + (wr + m * 16 + lr) * LDB + kb);
      af[m] = __builtin_bit_cast(bf16x8, raw);
    }
#pragma unroll
    for (int n = 0; n < 4; ++n) {
      u16x8 raw = *reinterpret_cast<const u16x8*>(BT + (wc + n * 16 + lr) * LDB + kb);
      bf_[n] = __builtin_bit_cast(bf16x8, raw);
    }
#pragma unroll
    for (int m = 0; m < 4; ++m)
#pragma unroll
      for (int n = 0; n < 4; ++n)
        acc[m][n] = __builtin_amdgcn_mfma_f32_16x16x32_bf16(af[m], bf_[n], acc[m][n], 0, 0, 0);
  }
}

// Pass 1: per chunk, KVT_c[e][d] = sum_tau v[tau][e] * k[tau][d] * exp(-sl*(128-tau))
__global__ __launch_bounds__(256) void la_kv(const float* __restrict__ k,
                                             const float* __restrict__ v,
                                             const float* __restrict__ s,
                                             float* __restrict__ ws) {
  __shared__ __align__(16) unsigned short kTs[128 * LDB];
  __shared__ __align__(16) unsigned short vT[128 * LDB];
  const int tid = threadIdx.x;
  const int bid = blockIdx.x;
  const int c   = bid & (NB - 1);
  const int bh  = bid >> 5;
  const float sl = s[bh & (HH - 1)];
  const size_t base = ((size_t)bh * NSEQ + (size_t)c * 128) * 128;

  stage_transpose_scaled(k + base, kTs, tid, sl);
  stage_transpose(v + base, vT, tid);
  __syncthreads();

  const int wid = tid >> 6, lane = tid & 63;
  const int wr = (wid >> 1) * 64, wc = (wid & 1) * 64;
  const int lr = lane & 15, lg = lane >> 4;

  f32x4 acc[4][4];
#pragma unroll
  for (int m = 0; m < 4; ++m)
#pragma unroll
    for (int n = 0; n < 4; ++n)
      acc[m][n] = (f32x4)0.f;

  // KVT = (v^T) @ (k scaled): A = vT[e][tau], B^T = kTs[d][tau]
  mm128(vT, kTs, lane, wr, wc, acc);

  float* dst = ws + ((size_t)bh * NB + c) * 16384;
#pragma unroll
  for (int m = 0; m < 4; ++m)
#pragma unroll
    for (int n = 0; n < 4; ++n)
#pragma unroll
      for (int r = 0; r < 4; ++r)
        dst[(wr + m * 16 + lg * 4 + r) * 128 + (wc + n * 16 + lr)] = acc[m][n][r];
}

// Pass 2: in-place decay scan over chunks. After: ws[c] = S^T at chunk START.
__global__ __launch_bounds__(256) void la_scan(const float* __restrict__ s,
                                               float* __restrict__ ws) {
  const int idx = blockIdx.x * 256 + threadIdx.x;  // 0 .. 2*16*16384-1
  const int bh  = idx >> 14;
  const int de  = idx & 16383;
  const float bd = expf(-s[bh & (HH - 1)] * 128.f);
  float* p = ws + (size_t)bh * NB * 16384 + de;
  float st = 0.f;
#pragma unroll
  for (int c = 0; c < NB; ++c) {
    float tmp = p[c * 16384];
    p[c * 16384] = st;
    st = st * bd + tmp;
  }
}

// Pass 3: per chunk, out = (q@k^T * intra_decay) @ v + diag(q_decay) * (q @ S)
__global__ __launch_bounds__(256) void la_out(const float* __restrict__ q,
                                              const float* __restrict__ k,
                                              const float* __restrict__ v,
                                              const float* __restrict__ s,
                                              const float* __restrict__ ws,
                                              float* __restrict__ out) {
  __shared__ __align__(16) unsigned short qs[128 * LDB];
  __shared__ __align__(16) unsigned short ksb[128 * LDB];  // k, later overwritten by P
  __shared__ __align__(16) unsigned short vT[128 * LDB];
  __shared__ __align__(16) unsigned short sT[128 * LDB];
  const int tid = threadIdx.x;
  const int bid = blockIdx.x;
  const int c   = bid & (NB - 1);
  const int bh  = bid >> 5;
  const float sl = s[bh & (HH - 1)];
  const size_t base = ((size_t)bh * NSEQ + (size_t)c * 128) * 128;

  stage_row(q + base, qs, tid);
  stage_row(k + base, ksb, tid);
  stage_transpose(v + base, vT, tid);
  stage_row(ws + ((size_t)bh * NB + c) * 16384, sT, tid);  // S^T row-major
  __syncthreads();

  const int wid = tid >> 6, lane = tid & 63;
  const int wr = (wid >> 1) * 64, wc = (wid & 1) * 64;
  const int lr = lane & 15, lg = lane >> 4;

  // scores = q @ k^T  (B^T = k row-major)
  f32x4 accS[4][4];
#pragma unroll
  for (int m = 0; m < 4; ++m)
#pragma unroll
    for (int n = 0; n < 4; ++n)
      accS[m][n] = (f32x4)0.f;
  mm128(qs, ksb, lane, wr, wc, accS);
  __syncthreads();  // everyone done reading k before P overwrites it

  // P = scores * intra_decay (causal), bf16, into ksb
#pragma unroll
  for (int m = 0; m < 4; ++m)
#pragma unroll
    for (int n = 0; n < 4; ++n)
#pragma unroll
      for (int r = 0; r < 4; ++r) {
        int t  = wr + m * 16 + lg * 4 + r;
        int sc = wc + n * 16 + lr;
        float pv = (t >= sc) ? accS[m][n][r] * expf(-sl * (float)(t - sc)) : 0.f;
        ksb[t * LDB + sc] = f2bf(pv);
      }
  __syncthreads();

  // acc2 = q @ S  (B^T = S^T), then row-scale by q_decay, then += P @ v
  f32x4 acc2[4][4];
#pragma unroll
  for (int m = 0; m < 4; ++m)
#pragma unroll
    for (int n = 0; n < 4; ++n)
      acc2[m][n] = (f32x4)0.f;
  mm128(qs, sT, lane, wr, wc, acc2);

#pragma unroll
  for (int m = 0; m < 4; ++m)
#pragma unroll
    for (int r = 0; r < 4; ++r) {
      float qd = expf(-sl * (float)(wr + m * 16 + lg * 4 + r));
#pragma unroll
      for (int n = 0; n < 4; ++n)
        acc2[m][n][r] *= qd;
    }

  mm128(ksb, vT, lane, wr, wc, acc2);

#pragma unroll
  for (int m = 0; m < 4; ++m)
#pragma unroll
    for (int n = 0; n < 4; ++n)
#pragma unroll
      for (int r = 0; r < 4; ++r)
        out[base + (size_t)(wr + m * 16 + lg * 4 + r) * 128 + (wc + n * 16 + lr)] =
            acc2[m][n][r];
}

extern "C" void kernel_launch(void* const* d_in, const int* in_sizes, int n_in,
                              void* d_out, int out_size, void* d_ws, size_t ws_size,
                              hipStream_t stream) {
  const float* q = (const float*)d_in[0];
  const float* k = (const float*)d_in[1];
  const float* v = (const float*)d_in[2];
  const float* s = (const float*)d_in[3];
  float* out = (float*)d_out;
  float* ws  = (float*)d_ws;   // needs 2*16*32*128*128*4 = 64 MiB

  la_kv<<<dim3(2 * HH * NB), dim3(256), 0, stream>>>(k, v, s, ws);
  la_scan<<<dim3(2 * HH * 16384 / 256), dim3(256), 0, stream>>>(s, ws);
  la_out<<<dim3(2 * HH * NB), dim3(256), 0, stream>>>(q, k, v, s, ws, out);
}

// Round 2
// 109.883 us; speedup vs baseline: 1.2565x; 1.2565x over previous
//
#include <hip/hip_runtime.h>
#include <hip/hip_bf16.h>

// Lightning attention, B=2 H=16 N=4096 D=128, BLOCK=128, nb=32.
// Pass 1 (la_kv):   per-chunk KV^T (bf16) via MFMA -> ws
// Pass 2 (la_scan): in-place decay scan over chunks (bf16 storage, fp32 accum)
// Pass 3 (la_out):  out = (q@k^T * intra_decay)@v + diag(q_decay)*(q@S)
//                   q,k,S fragments straight from global; only P and v^T in LDS.

#define LDB   136   // LDS row stride in u16 (272B: 16B-aligned, breaks worst conflicts)
#define NB    32
#define HH    16
#define NSEQ  4096

typedef float  f32x4  __attribute__((ext_vector_type(4)));
typedef __bf16 bf16x8 __attribute__((ext_vector_type(8)));
typedef unsigned short u16x8 __attribute__((ext_vector_type(8)));
typedef unsigned short u16x4 __attribute__((ext_vector_type(4)));

// float -> bf16 bits, round-to-nearest-even
__device__ __forceinline__ unsigned short f2bf(float f) {
  unsigned int u = __float_as_uint(f);
  unsigned int r = (u + 0x7fffu + ((u >> 16) & 1u)) >> 16;
  return (unsigned short)r;
}
__device__ __forceinline__ float bf2f(unsigned short h) {
  return __uint_as_float(((unsigned int)h) << 16);
}

// two float4 (8 consecutive floats) -> bf16x8
__device__ __forceinline__ bf16x8 cvt8(float4 a, float4 b) {
  bf16x8 r;
  r[0] = (__bf16)a.x; r[1] = (__bf16)a.y; r[2] = (__bf16)a.z; r[3] = (__bf16)a.w;
  r[4] = (__bf16)b.x; r[5] = (__bf16)b.y; r[6] = (__bf16)b.z; r[7] = (__bf16)b.w;
  return r;
}

// Stage 128x128 fp32 (row-major [tau][d]) -> LDS bf16 transposed [d][LDB]=src[tau][d].
__device__ __forceinline__ void stage_transpose(const float* __restrict__ src,
                                                unsigned short* dst, int tid) {
#pragma unroll
  for (int i = 0; i < 16; ++i) {
    int idx = i * 256 + tid;
    int d   = idx & 127;
    int tq  = idx >> 7;
    u16x4 w;
#pragma unroll
    for (int j = 0; j < 4; ++j)
      w[j] = f2bf(src[(tq * 4 + j) * 128 + d]);
    *reinterpret_cast<u16x4*>(dst + d * LDB + tq * 4) = w;
  }
}

// Same, but scale column tau by exp(-sl*(BLOCK - tau))  (k_decay).
__device__ __forceinline__ void stage_transpose_scaled(const float* __restrict__ src,
                                                       unsigned short* dst, int tid,
                                                       float sl) {
#pragma unroll
  for (int i = 0; i < 16; ++i) {
    int idx = i * 256 + tid;
    int d   = idx & 127;
    int tq  = idx >> 7;
    u16x4 w;
#pragma unroll
    for (int j = 0; j < 4; ++j) {
      int tau = tq * 4 + j;
      float kd = expf(-sl * (float)(128 - tau));
      w[j] = f2bf(src[tau * 128 + d] * kd);
    }
    *reinterpret_cast<u16x4*>(dst + d * LDB + tq * 4) = w;
  }
}

// 128x128x128 matmul from LDS: D += A * B with BT = B^T row-major in LDS.
__device__ __forceinline__ void mm128(const unsigned short* A, const unsigned short* BT,
                                      int lane, int wr, int wc, f32x4 acc[4][4]) {
  const int lr = lane & 15;
  const int lg = lane >> 4;
#pragma unroll
  for (int kk = 0; kk < 4; ++kk) {
    const int kb = kk * 32 + lg * 8;
    bf16x8 af[4], bf_[4];
#pragma unroll
    for (int m = 0; m < 4; ++m) {
      u16x8 raw = *reinterpret_cast<const u16x8*>(A + (wr + m * 16 + lr) * LDB + kb);
      af[m] = __builtin_bit_cast(bf16x8, raw);
    }
#pragma unroll
    for (int n = 0; n < 4; ++n) {
      u16x8 raw = *reinterpret_cast<const u16x8*>(BT + (wc + n * 16 + lr) * LDB + kb);
      bf_[n] = __builtin_bit_cast(bf16x8, raw);
    }
#pragma unroll
    for (int m = 0; m < 4; ++m)
#pragma unroll
      for (int n = 0; n < 4; ++n)
        acc[m][n] = __builtin_amdgcn_mfma_f32_16x16x32_bf16(af[m], bf_[n], acc[m][n], 0, 0, 0);
  }
}

// Pass 1: KVT_c[e][d] = sum_tau v[tau][e] * k[tau][d] * exp(-sl*(128-tau)) -> bf16 ws
__global__ __launch_bounds__(256) void la_kv(const float* __restrict__ k,
                                             const float* __restrict__ v,
                                             const float* __restrict__ s,
                                             unsigned short* __restrict__ ws) {
  __shared__ __align__(16) unsigned short kTs[128 * LDB];
  __shared__ __align__(16) unsigned short vT[128 * LDB];
  const int tid = threadIdx.x;
  const int bid = blockIdx.x;
  const int c   = bid & (NB - 1);
  const int bh  = bid >> 5;
  const float sl = s[bh & (HH - 1)];
  const size_t base = ((size_t)bh * NSEQ + (size_t)c * 128) * 128;

  stage_transpose_scaled(k + base, kTs, tid, sl);
  stage_transpose(v + base, vT, tid);
  __syncthreads();

  const int wid = tid >> 6, lane = tid & 63;
  const int wr = (wid >> 1) * 64, wc = (wid & 1) * 64;
  const int lr = lane & 15, lg = lane >> 4;

  f32x4 acc[4][4];
#pragma unroll
  for (int m = 0; m < 4; ++m)
#pragma unroll
    for (int n = 0; n < 4; ++n)
      acc[m][n] = (f32x4)0.f;

  mm128(vT, kTs, lane, wr, wc, acc);

  unsigned short* dst = ws + ((size_t)bh * NB + c) * 16384;
#pragma unroll
  for (int m = 0; m < 4; ++m)
#pragma unroll
    for (int n = 0; n < 4; ++n)
#pragma unroll
      for (int r = 0; r < 4; ++r)
        dst[(wr + m * 16 + lg * 4 + r) * 128 + (wc + n * 16 + lr)] = f2bf(acc[m][n][r]);
}

// Pass 2: in-place decay scan (bf16 storage, fp32 accumulator).
__global__ __launch_bounds__(256) void la_scan(const float* __restrict__ s,
                                               unsigned short* __restrict__ ws) {
  const int idx = blockIdx.x * 256 + threadIdx.x;  // 0 .. 2*16*16384-1
  const int bh  = idx >> 14;
  const int de  = idx & 16383;
  const float bd = expf(-s[bh & (HH - 1)] * 128.f);
  unsigned short* p = ws + (size_t)bh * NB * 16384 + de;
  float st = 0.f;
#pragma unroll
  for (int c = 0; c < NB; ++c) {
    float tmp = bf2f(p[c * 16384]);
    p[c * 16384] = f2bf(st);
    st = st * bd + tmp;
  }
}

// Pass 3: out = (q@k^T * intra_decay)@v + diag(q_decay)*(q@S)
__global__ __launch_bounds__(256) void la_out(const float* __restrict__ q,
                                              const float* __restrict__ k,
                                              const float* __restrict__ v,
                                              const float* __restrict__ s,
                                              const unsigned short* __restrict__ ws,
                                              float* __restrict__ out) {
  __shared__ __align__(16) unsigned short Pb[128 * LDB];
  __shared__ __align__(16) unsigned short vT[128 * LDB];
  const int tid = threadIdx.x;
  const int bid = blockIdx.x;
  const int c   = bid & (NB - 1);
  const int bh  = bid >> 5;
  const float sl = s[bh & (HH - 1)];
  const size_t base = ((size_t)bh * NSEQ + (size_t)c * 128) * 128;

  // stage v^T early (only LDS-transposed operand besides P)
  stage_transpose(v + base, vT, tid);

  const int wid = tid >> 6, lane = tid & 63;
  const int wr = (wid >> 1) * 64, wc = (wid & 1) * 64;
  const int lr = lane & 15, lg = lane >> 4;

  // scores = q @ k^T, fragments straight from global fp32
  f32x4 accS[4][4];
#pragma unroll
  for (int m = 0; m < 4; ++m)
#pragma unroll
    for (int n = 0; n < 4; ++n)
      accS[m][n] = (f32x4)0.f;

  bf16x8 qf[4][4];  // [kk][m], kept live for the q@S matmul
#pragma unroll
  for (int kk = 0; kk < 4; ++kk) {
    const int kb = kk * 32 + lg * 8;
#pragma unroll
    for (int m = 0; m < 4; ++m) {
      const float* p = q + base + (size_t)(wr + m * 16 + lr) * 128 + kb;
      qf[kk][m] = cvt8(*reinterpret_cast<const float4*>(p),
                       *reinterpret_cast<const float4*>(p + 4));
    }
    bf16x8 kf[4];
#pragma unroll
    for (int n = 0; n < 4; ++n) {
      const float* p = k + base + (size_t)(wc + n * 16 + lr) * 128 + kb;
      kf[n] = cvt8(*reinterpret_cast<const float4*>(p),
                   *reinterpret_cast<const float4*>(p + 4));
    }
#pragma unroll
    for (int m = 0; m < 4; ++m)
#pragma unroll
      for (int n = 0; n < 4; ++n)
        accS[m][n] = __builtin_amdgcn_mfma_f32_16x16x32_bf16(qf[kk][m], kf[n], accS[m][n], 0, 0, 0);
  }

  // P = scores * intra_decay (causal), bf16 -> LDS
#pragma unroll
  for (int m = 0; m < 4; ++m)
#pragma unroll
    for (int n = 0; n < 4; ++n)
#pragma unroll
      for (int r = 0; r < 4; ++r) {
        int t  = wr + m * 16 + lg * 4 + r;
        int sc = wc + n * 16 + lr;
        float pv = (t >= sc) ? accS[m][n][r] * expf(-sl * (float)(t - sc)) : 0.f;
        Pb[t * LDB + sc] = f2bf(pv);
      }

  // acc2 = q @ S, S^T fragments straight from global bf16 ws
  const unsigned short* Sp = ws + ((size_t)bh * NB + c) * 16384;
  f32x4 acc2[4][4];
#pragma unroll
  for (int m = 0; m < 4; ++m)
#pragma unroll
    for (int n = 0; n < 4; ++n)
      acc2[m][n] = (f32x4)0.f;

#pragma unroll
  for (int kk = 0; kk < 4; ++kk) {
    const int kb = kk * 32 + lg * 8;
    bf16x8 sf[4];
#pragma unroll
    for (int n = 0; n < 4; ++n) {
      u16x8 raw = *reinterpret_cast<const u16x8*>(Sp + (size_t)(wc + n * 16 + lr) * 128 + kb);
      sf[n] = __builtin_bit_cast(bf16x8, raw);
    }
#pragma unroll
    for (int m = 0; m < 4; ++m)
#pragma unroll
      for (int n = 0; n < 4; ++n)
        acc2[m][n] = __builtin_amdgcn_mfma_f32_16x16x32_bf16(qf[kk][m], sf[n], acc2[m][n], 0, 0, 0);
  }

  // row-scale by q_decay
#pragma unroll
  for (int m = 0; m < 4; ++m)
#pragma unroll
    for (int r = 0; r < 4; ++r) {
      float qd = expf(-sl * (float)(wr + m * 16 + lg * 4 + r));
#pragma unroll
      for (int n = 0; n < 4; ++n)
        acc2[m][n][r] *= qd;
    }

  __syncthreads();  // P fully written (all waves) + vT staged

  // acc2 += P @ v
  mm128(Pb, vT, lane, wr, wc, acc2);

#pragma unroll
  for (int m = 0; m < 4; ++m)
#pragma unroll
    for (int n = 0; n < 4; ++n)
#pragma unroll
      for (int r = 0; r < 4; ++r)
        out[base + (size_t)(wr + m * 16 + lg * 4 + r) * 128 + (wc + n * 16 + lr)] =
            acc2[m][n][r];
}

extern "C" void kernel_launch(void* const* d_in, const int* in_sizes, int n_in,
                              void* d_out, int out_size, void* d_ws, size_t ws_size,
                              hipStream_t stream) {
  const float* q = (const float*)d_in[0];
  const float* k = (const float*)d_in[1];
  const float* v = (const float*)d_in[2];
  const float* s = (const float*)d_in[3];
  float* out = (float*)d_out;
  unsigned short* ws = (unsigned short*)d_ws;  // 2*16*32*128*128*2 = 32 MiB

  la_kv<<<dim3(2 * HH * NB), dim3(256), 0, stream>>>(k, v, s, ws);
  la_scan<<<dim3(2 * HH * 16384 / 256), dim3(256), 0, stream>>>(s, ws);
  la_out<<<dim3(2 * HH * NB), dim3(256), 0, stream>>>(q, k, v, s, ws, out);
}